// Round 2
// baseline (212.911 us; speedup 1.0000x reference)
//
#include <hip/hip_runtime.h>
#include <math.h>

#define B_DIM 512
#define T_DIM 256
#define C_DIM 400
#define EPSV 1e-8f
#define U 8   // time-steps per barrier round

// ---------------------------------------------------------------------------
// Fused kernel: one block per b (512 threads, thread = class c).
// Per round of U=8 time-steps:
//   A) 8 independent wave max-reduces -> LDS partials -> barrier
//   B) block max, exp, 8 wave sum-reduces -> LDS partials -> barrier
//   C) block sum, p = exp/sum, in-order cummax/argmax/sum-cummax update
// x is read exactly once (single-pass). Scan state lives in registers.
// ---------------------------------------------------------------------------
__global__ __launch_bounds__(512) void fused_scan_kernel(
    const float* __restrict__ x, float* __restrict__ out) {
    __shared__ float pmax[U][8];
    __shared__ float psum[U][8];

    const int  b   = blockIdx.x;
    const int  tid = threadIdx.x;
    const int  wv  = tid >> 6;
    const int  ln  = tid & 63;
    const int  c   = tid;
    const bool act = (c < C_DIM);

    const float* xb = x + (size_t)b * T_DIM * C_DIM + c;

    // double-buffered prefetch: vc = current U rows, vn = next U rows
    float vc[U], vn[U];
    #pragma unroll
    for (int u = 0; u < U; ++u)
        vc[u] = act ? xb[(size_t)u * C_DIM] : -INFINITY;

    float  cur = -1.0f;   // running max of clamped proba
    int    arg = 0;       // first argmax over t
    double scm = 0.0;     // sum of cummax (double: cancellation in e_x)

    for (int t0 = 0; t0 < T_DIM; t0 += U) {
        // issue next round's loads early (hide HBM latency under reduces)
        #pragma unroll
        for (int u = 0; u < U; ++u) {
            int tn = t0 + U + u;
            vn[u] = (tn < T_DIM && act) ? xb[(size_t)tn * C_DIM] : -INFINITY;
        }

        // phase A: per-wave max partials (8 independent shuffle chains)
        #pragma unroll
        for (int u = 0; u < U; ++u) {
            float m = vc[u];
            #pragma unroll
            for (int off = 32; off > 0; off >>= 1)
                m = fmaxf(m, __shfl_xor(m, off, 64));
            if (ln == 0) pmax[u][wv] = m;
        }
        __syncthreads();

        // phase B: block max -> exp -> per-wave sum partials
        float e[U];
        #pragma unroll
        for (int u = 0; u < U; ++u) {
            float bm = pmax[u][0];
            #pragma unroll
            for (int i = 1; i < 8; ++i) bm = fmaxf(bm, pmax[u][i]);
            e[u] = expf(vc[u] - bm);          // 0 for inactive lanes (-inf)
            float s = e[u];
            #pragma unroll
            for (int off = 32; off > 0; off >>= 1)
                s += __shfl_xor(s, off, 64);
            if (ln == 0) psum[u][wv] = s;
        }
        __syncthreads();

        // phase C: block sum, probability, in-t-order scan update
        #pragma unroll
        for (int u = 0; u < U; ++u) {
            float bs = psum[u][0];
            #pragma unroll
            for (int i = 1; i < 8; ++i) bs += psum[u][i];
            float p = fmaxf(e[u] / bs, EPSV);
            if (p > cur) { cur = p; arg = t0 + u; }
            scm += (double)cur;
        }

        #pragma unroll
        for (int u = 0; u < U; ++u) vc[u] = vn[u];
    }

    if (act) {
        float  maxp = fmaxf(cur, EPSV);
        double e_x  = (double)T_DIM - scm / (double)maxp;
        size_t BC = (size_t)B_DIM * C_DIM;
        size_t o  = (size_t)b * C_DIM + c;
        out[1 + o]          = (float)arg;   // idx
        out[1 + BC + o]     = maxp;         // max_probs
        out[1 + 2 * BC + o] = (float)e_x;   // e_x
    }
}

// ---------------------------------------------------------------------------
// Loss: fast_loss = mean_b [ -log(maxp[b,lab]) + log(e_x[b,lab]/T + EPS) ]
// ---------------------------------------------------------------------------
__global__ __launch_bounds__(512) void loss_kernel(
    const int* __restrict__ labels, float* __restrict__ out) {
    __shared__ double part[8];
    int b = threadIdx.x;
    size_t BC = (size_t)B_DIM * C_DIM;

    int    lab  = labels[b];
    float  maxp = out[1 + BC + (size_t)b * C_DIM + lab];
    float  e_x  = out[1 + 2 * BC + (size_t)b * C_DIM + lab];
    double i_x  = (double)e_x / (double)T_DIM;
    double pc   = -log((double)maxp) + log(i_x + 1e-8);

    #pragma unroll
    for (int off = 32; off > 0; off >>= 1)
        pc += __shfl_xor(pc, off, 64);

    if ((threadIdx.x & 63) == 0) part[threadIdx.x >> 6] = pc;
    __syncthreads();
    if (threadIdx.x == 0) {
        double s = 0.0;
        #pragma unroll
        for (int i = 0; i < 8; ++i) s += part[i];
        out[0] = (float)(s / (double)B_DIM);
    }
}

extern "C" void kernel_launch(void* const* d_in, const int* in_sizes, int n_in,
                              void* d_out, int out_size, void* d_ws, size_t ws_size,
                              hipStream_t stream) {
    const float* x      = (const float*)d_in[0];
    const int*   labels = (const int*)d_in[1];
    float*       out    = (float*)d_out;

    fused_scan_kernel<<<B_DIM, 512, 0, stream>>>(x, out);
    loss_kernel<<<1, 512, 0, stream>>>(labels, out);
}

// Round 3
// 111.080 us; speedup vs baseline: 1.9167x; 1.9167x over previous
//
#include <hip/hip_runtime.h>
#include <math.h>

#define B_DIM 512
#define T_DIM 256
#define C_DIM 400
#define EPSV 1e-8f
#define TT 16                  // t-rows per LDS tile
#define NT (T_DIM / TT)        // 16 tiles
#define TILE_F (TT * C_DIM)    // 6400 floats per tile
#define WAVE_F4 200            // float4s staged per wave per tile (1600/8)

// ---------------------------------------------------------------------------
// Stage one 16-row tile (51.2 KB) into LDS via async global_load_lds (16 B).
// Wave w owns float4 range [w*200, w*200+200): 3 full-wave calls + 8 lanes.
// LDS dest is wave-uniform base + lane*16 (linear layout, no swizzle needed).
// ---------------------------------------------------------------------------
__device__ __forceinline__ void stage_tile(const float* __restrict__ xb,
                                           float* buf, int tile, int w, int ln) {
    const float* src = xb + (size_t)tile * TILE_F;
    #pragma unroll
    for (int k = 0; k < 3; ++k) {
        int f4i = w * WAVE_F4 + k * 64;   // wave-uniform float4 index
        __builtin_amdgcn_global_load_lds(
            (const __attribute__((address_space(1))) void*)(src + (size_t)(f4i + ln) * 4),
            (__attribute__((address_space(3))) void*)(buf + (size_t)f4i * 4),
            16, 0, 0);
    }
    int f4i = w * WAVE_F4 + 192;
    if (ln < 8)
        __builtin_amdgcn_global_load_lds(
            (const __attribute__((address_space(1))) void*)(src + (size_t)(f4i + ln) * 4),
            (__attribute__((address_space(3))) void*)(buf + (size_t)f4i * 4),
            16, 0, 0);
}

// ---------------------------------------------------------------------------
// Fused single-read kernel: one block (512 thr) per b.
// Per tile: [issue next stage | vmcnt(4) | bar] [wave row-stats | bar]
//           [per-c scan from LDS | bar]
// Raw s_barrier + counted vmcnt keeps next tile's loads in flight (T4).
// ---------------------------------------------------------------------------
__global__ __launch_bounds__(512) void fused_kernel(
    const float* __restrict__ x, float* __restrict__ out) {
    __shared__ float buf[2][TILE_F];
    __shared__ float rm_s[TT];
    __shared__ float rs_s[TT];

    const int  b   = blockIdx.x;
    const int  tid = threadIdx.x;
    const int  w   = tid >> 6;
    const int  ln  = tid & 63;
    const int  c   = tid;
    const bool act = (c < C_DIM);
    const float* xb = x + (size_t)b * T_DIM * C_DIM;

    float  cur = -1.0f;   // running max of clamped proba
    int    arg = 0;       // first argmax over t
    double scm = 0.0;     // sum of cummax (double: cancellation in e_x)

    stage_tile(xb, &buf[0][0], 0, w, ln);

    int curb = 0;
    for (int tile = 0; tile < NT; ++tile) {
        if (tile + 1 < NT) {
            stage_tile(xb, &buf[curb ^ 1][0], tile + 1, w, ln);
            asm volatile("s_waitcnt vmcnt(4)" ::: "memory");   // cur tile landed
        } else {
            asm volatile("s_waitcnt vmcnt(0)" ::: "memory");
        }
        __builtin_amdgcn_sched_barrier(0);
        __builtin_amdgcn_s_barrier();                          // A: tile staged

        // --- row stats: wave w owns rows {2w, 2w+1}; 7 regs/lane + shuffle tree
        const float* bp = &buf[curb][0];
        #pragma unroll
        for (int rr = 0; rr < 2; ++rr) {
            int r = w * 2 + rr;
            float v[7];
            float m = -INFINITY;
            #pragma unroll
            for (int k = 0; k < 7; ++k) {
                int cc = ln + k * 64;
                v[k] = (cc < C_DIM) ? bp[r * C_DIM + cc] : -INFINITY;
                m = fmaxf(m, v[k]);
            }
            #pragma unroll
            for (int off = 32; off > 0; off >>= 1)
                m = fmaxf(m, __shfl_xor(m, off, 64));
            float s = 0.f;
            #pragma unroll
            for (int k = 0; k < 7; ++k)
                if (ln + k * 64 < C_DIM) s += expf(v[k] - m);
            #pragma unroll
            for (int off = 32; off > 0; off >>= 1)
                s += __shfl_xor(s, off, 64);
            if (ln == 0) { rm_s[r] = m; rs_s[r] = s; }
        }
        asm volatile("s_waitcnt lgkmcnt(0)" ::: "memory");
        __builtin_amdgcn_sched_barrier(0);
        __builtin_amdgcn_s_barrier();                          // B: stats ready

        // --- scan: thread c walks its column within the tile
        if (act) {
            #pragma unroll 4
            for (int t = 0; t < TT; ++t) {
                float p = expf(bp[t * C_DIM + c] - rm_s[t]) / rs_s[t];
                p = fmaxf(p, EPSV);
                if (p > cur) { cur = p; arg = tile * TT + t; }
                scm += (double)cur;
            }
        }
        asm volatile("s_waitcnt lgkmcnt(0)" ::: "memory");
        __builtin_amdgcn_sched_barrier(0);
        __builtin_amdgcn_s_barrier();                          // C: done with buf
        curb ^= 1;
    }

    if (act) {
        float  maxp = fmaxf(cur, EPSV);
        double e_x  = (double)T_DIM - scm / (double)maxp;
        size_t BC = (size_t)B_DIM * C_DIM;
        size_t o  = (size_t)b * C_DIM + c;
        out[1 + o]          = (float)arg;   // idx
        out[1 + BC + o]     = maxp;         // max_probs
        out[1 + 2 * BC + o] = (float)e_x;   // e_x
    }
}

// ---------------------------------------------------------------------------
// Loss: fast_loss = mean_b [ -log(maxp[b,lab]) + log(e_x[b,lab]/T + EPS) ]
// ---------------------------------------------------------------------------
__global__ __launch_bounds__(512) void loss_kernel(
    const int* __restrict__ labels, float* __restrict__ out) {
    __shared__ double part[8];
    int b = threadIdx.x;
    size_t BC = (size_t)B_DIM * C_DIM;

    int    lab  = labels[b];
    float  maxp = out[1 + BC + (size_t)b * C_DIM + lab];
    float  e_x  = out[1 + 2 * BC + (size_t)b * C_DIM + lab];
    double i_x  = (double)e_x / (double)T_DIM;
    double pc   = -log((double)maxp) + log(i_x + 1e-8);

    #pragma unroll
    for (int off = 32; off > 0; off >>= 1)
        pc += __shfl_xor(pc, off, 64);

    if ((threadIdx.x & 63) == 0) part[threadIdx.x >> 6] = pc;
    __syncthreads();
    if (threadIdx.x == 0) {
        double s = 0.0;
        #pragma unroll
        for (int i = 0; i < 8; ++i) s += part[i];
        out[0] = (float)(s / (double)B_DIM);
    }
}

extern "C" void kernel_launch(void* const* d_in, const int* in_sizes, int n_in,
                              void* d_out, int out_size, void* d_ws, size_t ws_size,
                              hipStream_t stream) {
    const float* x      = (const float*)d_in[0];
    const int*   labels = (const int*)d_in[1];
    float*       out    = (float*)d_out;

    fused_kernel<<<B_DIM, 512, 0, stream>>>(x, out);
    loss_kernel<<<1, 512, 0, stream>>>(labels, out);
}

// Round 4
// 57.489 us; speedup vs baseline: 3.7035x; 1.9322x over previous
//
#include <hip/hip_runtime.h>
#include <math.h>

#define B_DIM 512
#define T_DIM 256
#define C_DIM 400
#define EPSV 1e-8f
#define TT 16                   // t-rows per tile
#define NT (T_DIM / TT)         // 16 tiles
#define TILE_F (TT * C_DIM)     // 6400 floats per tile (25.6 KB)

// Row layout: 400 floats = 100 float4. Lane ln owns f4[ln] (all lanes) and
// f4[64+ln] (lanes < 36). Global loads are fully coalesced (16 B/lane).

__device__ __forceinline__ float4 ninf4() {
    return make_float4(-INFINITY, -INFINITY, -INFINITY, -INFINITY);
}

__device__ __forceinline__ void load_tile_rows(
    const float* __restrict__ xb, int tile, int w, int ln,
    float4& a0, float4& a1, float4& b0, float4& b1) {
    const float4* r0 = (const float4*)(xb + (size_t)tile * TILE_F + (size_t)(2 * w) * C_DIM);
    const float4* r1 = (const float4*)(xb + (size_t)tile * TILE_F + (size_t)(2 * w + 1) * C_DIM);
    a0 = r0[ln];
    b0 = r1[ln];
    a1 = ninf4();
    b1 = ninf4();
    if (ln < 36) { a1 = r0[64 + ln]; b1 = r1[64 + ln]; }
}

// Softmax one row from registers; store p = exp(v-m)/s into LDS row (b128).
__device__ __forceinline__ void row_softmax_store(
    float4 v0, float4 v1, float* __restrict__ rowp, int ln) {
    float m = fmaxf(fmaxf(fmaxf(v0.x, v0.y), fmaxf(v0.z, v0.w)),
                    fmaxf(fmaxf(v1.x, v1.y), fmaxf(v1.z, v1.w)));
    #pragma unroll
    for (int off = 32; off > 0; off >>= 1)
        m = fmaxf(m, __shfl_xor(m, off, 64));

    float e0x = __expf(v0.x - m), e0y = __expf(v0.y - m);
    float e0z = __expf(v0.z - m), e0w = __expf(v0.w - m);
    float e1x = __expf(v1.x - m), e1y = __expf(v1.y - m);   // 0 for -inf lanes
    float e1z = __expf(v1.z - m), e1w = __expf(v1.w - m);

    float s = ((e0x + e0y) + (e0z + e0w)) + ((e1x + e1y) + (e1z + e1w));
    #pragma unroll
    for (int off = 32; off > 0; off >>= 1)
        s += __shfl_xor(s, off, 64);

    float rinv = 1.0f / s;                      // one IEEE div per row
    float4* wp = (float4*)rowp;
    wp[ln] = make_float4(e0x * rinv, e0y * rinv, e0z * rinv, e0w * rinv);
    if (ln < 36)
        wp[64 + ln] = make_float4(e1x * rinv, e1y * rinv, e1z * rinv, e1w * rinv);
}

// ---------------------------------------------------------------------------
// Fused kernel: one block (512 thr) per b. Per tile:
//   [issue next tile's global loads to regs] [stats on current regs -> p in LDS]
//   [lgkmcnt(0); s_barrier]  [scan: per-c cummax chain from LDS]
// One barrier per tile; double-buffered p so scan(i) overlaps stats(i+1).
// ---------------------------------------------------------------------------
__global__ __launch_bounds__(512, 4) void fused_kernel(
    const float* __restrict__ x, const int* __restrict__ labels,
    float* __restrict__ out, double* __restrict__ pcws) {
    __shared__ __align__(16) float buf[2][TILE_F];

    const int b   = blockIdx.x;
    const int tid = threadIdx.x;
    const int w   = tid >> 6;
    const int ln  = tid & 63;
    const int c   = w * 50 + ln;      // balanced scan columns: 50 per wave
    const bool act = (ln < 50);
    const float* xb = x + (size_t)b * T_DIM * C_DIM;

    float4 ca0, ca1, cb0, cb1, na0, na1, nb0, nb1;
    load_tile_rows(xb, 0, w, ln, ca0, ca1, cb0, cb1);

    float  cur = -1.0f;   // running cummax of clamped p
    int    arg = 0;       // first argmax over t
    double scm = 0.0;     // sum of cummax (double: exact when argmax at t=0)

    for (int tile = 0; tile < NT; ++tile) {
        const int pb = tile & 1;
        if (tile + 1 < NT)
            load_tile_rows(xb, tile + 1, w, ln, na0, na1, nb0, nb1);

        // stats: this wave's two rows -> p written to buf[pb]
        row_softmax_store(ca0, ca1, &buf[pb][(size_t)(2 * w) * C_DIM], ln);
        row_softmax_store(cb0, cb1, &buf[pb][(size_t)(2 * w + 1) * C_DIM], ln);

        asm volatile("s_waitcnt lgkmcnt(0)" ::: "memory");
        __builtin_amdgcn_sched_barrier(0);
        __builtin_amdgcn_s_barrier();          // p(tile) visible to all waves

        // scan: thread's column over the tile's 16 t's
        if (act) {
            const float* bp = &buf[pb][c];
            #pragma unroll
            for (int t = 0; t < TT; ++t) {
                float p = fmaxf(bp[(size_t)t * C_DIM], EPSV);
                if (p > cur) { cur = p; arg = tile * TT + t; }
                scm += (double)cur;
            }
        }
        ca0 = na0; ca1 = na1; cb0 = nb0; cb1 = nb1;
    }

    if (act) {
        float  maxp = fmaxf(cur, EPSV);
        double e_x  = (double)T_DIM - scm / (double)maxp;
        size_t BC = (size_t)B_DIM * C_DIM;
        size_t o  = (size_t)b * C_DIM + c;
        out[1 + o]          = (float)arg;   // idx
        out[1 + BC + o]     = maxp;         // max_probs
        out[1 + 2 * BC + o] = (float)e_x;   // e_x
        if (c == labels[b]) {
            double i_x = e_x / (double)T_DIM;
            pcws[b] = -log((double)maxp) + log(i_x + 1e-8);
        }
    }
}

// ---------------------------------------------------------------------------
// Loss: mean of 512 per-b per-class terms.
// ---------------------------------------------------------------------------
__global__ __launch_bounds__(512) void loss_kernel(
    const double* __restrict__ pcws, float* __restrict__ out) {
    __shared__ double part[8];
    double pc = pcws[threadIdx.x];
    #pragma unroll
    for (int off = 32; off > 0; off >>= 1)
        pc += __shfl_xor(pc, off, 64);
    if ((threadIdx.x & 63) == 0) part[threadIdx.x >> 6] = pc;
    __syncthreads();
    if (threadIdx.x == 0) {
        double s = 0.0;
        #pragma unroll
        for (int i = 0; i < 8; ++i) s += part[i];
        out[0] = (float)(s / (double)B_DIM);
    }
}

extern "C" void kernel_launch(void* const* d_in, const int* in_sizes, int n_in,
                              void* d_out, int out_size, void* d_ws, size_t ws_size,
                              hipStream_t stream) {
    const float* x      = (const float*)d_in[0];
    const int*   labels = (const int*)d_in[1];
    float*       out    = (float*)d_out;
    double*      pcws   = (double*)d_ws;   // 512 doubles

    fused_kernel<<<B_DIM, 512, 0, stream>>>(x, labels, out, pcws);
    loss_kernel<<<1, 512, 0, stream>>>(pcws, out);
}